// Round 4
// baseline (199.741 us; speedup 1.0000x reference)
//
#include <hip/hip_runtime.h>
#include <hip/hip_fp16.h>

// PillarMaxPooling R16: one-line-per-pillar output via packed-f16 CAS-max.
// Triangulation: R13 (ops x2.8 -> +10% time) => atomic OPS not binding;
// R14 (record scatter 96MB/75us) => ANY random 128B-per-point write costs
// ~75-95us; R15 (deep pipeline, VALU 33->42%) => latency not binding.
// => binding resource is RANDOM DIRTY LINES: 2 per point (32ch x 4B = 128B).
// Fix: 16-bit f16 encodings -> 32ch x 2B = 64B = ONE line per pillar.
// Lane pairs pack 2 channels/word; even lanes do read-filtered CAS-max
// (no write when no improvement; ~6.6 updates/word lifetime -> retries nil).
// f16 RN is monotone => max(round(x)) == round(max(x)); added error ~2^-11
// rel on N(0,1)-normalized outputs => absmax +~0.003 over current 0.0156.
// Keep R12 skeleton: half-wave/point, sidx prefetch only (R15: deeper
// prefetch hurts), folded weights, f32 stats, NT loads on streams.
// Ledger: R12 85.8us scatter/172 total (prev best); R13 no-filter 94; R14
// bucket 286; R15 pipelined 92. Harness constant ~85us. ws >= 29MB (R14).

#define CMLP 32
#define BN_EPS 1e-3f
#define PSIZE 0.075f
#define XMIN -54.0f
#define YMIN -54.0f
#define CZ   -1.0f   // 0.5*(Z_MIN+Z_MAX)
#define NREP 64      // stats replicas (64 lines apart)
#define SCATB 4096

// monotone f16<->u16 order map; u==0 unreachable from finite data -> sentinel
__device__ __forceinline__ unsigned enc16(float x) {
  unsigned short b = __half_as_ushort(__float2half(x));  // RN, monotone
  unsigned short e = (b & 0x8000) ? (unsigned short)~b
                                  : (unsigned short)(b | 0x8000);
  return (unsigned)e;
}
__device__ __forceinline__ float dec16(unsigned u) {
  unsigned short e = (unsigned short)u;
  unsigned short b = (e & 0x8000) ? (unsigned short)(e & 0x7FFF)
                                  : (unsigned short)~e;
  return __half2float(__ushort_as_half(b));
}

__global__ void __launch_bounds__(256) scatter_stats_kernel(
    const float* __restrict__ xyz, const float* __restrict__ ptf,
    const float* __restrict__ W1, const float* __restrict__ gamma,
    const int* __restrict__ pil, const int* __restrict__ sidx,
    float* __restrict__ stats_rep, unsigned* __restrict__ out16w, int N) {
  const int tid = threadIdx.x;
  const int c = tid & 31;
  // folded weights: h = x*wx + y*wy + z*wz - cx*w0 - cy*w1 - CZ*w2 + ptf.w
  const float w0 = W1[0 * CMLP + c], w1 = W1[1 * CMLP + c];
  const float w2 = W1[2 * CMLP + c];
  const float wx = w0 + W1[3 * CMLP + c];
  const float wy = w1 + W1[4 * CMLP + c];
  const float wz = w2 + W1[5 * CMLP + c];
  const float nw0 = -w0, nw1 = -w1;
  const float c0 = -CZ * w2;
  const float w6 = W1[6 * CMLP + c], w7 = W1[7 * CMLP + c];
  const float w8 = W1[8 * CMLP + c], w9 = W1[9 * CMLP + c];
  const float w10 = W1[10 * CMLP + c];
  const float sgn = (gamma[c] < 0.f) ? -1.f : 1.f;  // sign(sc)=sign(gamma)
  float s = 0.f, ss = 0.f;  // per-channel h moments (f32, unchanged)
  // half-wave per point; 32 lanes issue the same addresses -> HW broadcast
  const int hw0 = (blockIdx.x * 256 + tid) >> 5;
  const int nhw = (SCATB * 256) >> 5;
  int p = hw0;
  int m = (p < N) ? __builtin_nontemporal_load(&sidx[p]) : 0;
  while (p < N) {
    const int pn = p + nhw;
    const int mn = (pn < N) ? __builtin_nontemporal_load(&sidx[pn]) : 0;
    float cx = fmaf((float)pil[3 * m + 2] + 0.5f, PSIZE, XMIN);
    float cy = fmaf((float)pil[3 * m + 1] + 0.5f, PSIZE, YMIN);
    float x = __builtin_nontemporal_load(&xyz[3 * p]);
    float y = __builtin_nontemporal_load(&xyz[3 * p + 1]);
    float z = __builtin_nontemporal_load(&xyz[3 * p + 2]);
    float h = c0;
    h = fmaf(x, wx, h);
    h = fmaf(y, wy, h);
    h = fmaf(z, wz, h);
    h = fmaf(cx, nw0, h);
    h = fmaf(cy, nw1, h);
    h = fmaf(__builtin_nontemporal_load(&ptf[5 * p + 0]), w6, h);
    h = fmaf(__builtin_nontemporal_load(&ptf[5 * p + 1]), w7, h);
    h = fmaf(__builtin_nontemporal_load(&ptf[5 * p + 2]), w8, h);
    h = fmaf(__builtin_nontemporal_load(&ptf[5 * p + 3]), w9, h);
    h = fmaf(__builtin_nontemporal_load(&ptf[5 * p + 4]), w10, h);
    s += h;
    ss = fmaf(h, h, ss);
    // ---- packed-f16 CAS-max: even lane owns word (channels c, c+1) ----
    unsigned e = enc16(sgn * h);
    unsigned partner = (unsigned)__shfl_xor((int)e, 1);
    if ((c & 1) == 0) {
      unsigned* addr = &out16w[m * (CMLP / 2) + (c >> 1)];
      unsigned cur = *addr;  // read-filter; stale -> CAS retry fixes up
      unsigned lo = e > (cur & 0xFFFFu) ? e : (cur & 0xFFFFu);
      unsigned hi = partner > (cur >> 16) ? partner : (cur >> 16);
      unsigned des = lo | (hi << 16);
      while (des != cur) {
        unsigned old = atomicCAS(addr, cur, des);
        if (old == cur) break;
        cur = old;
        lo = e > (cur & 0xFFFFu) ? e : (cur & 0xFFFFu);
        hi = partner > (cur >> 16) ? partner : (cur >> 16);
        des = lo | (hi << 16);
      }
    }
    p = pn;
    m = mn;
  }
  // lanes L and L+32 hold the same channel -> combine, stage, block-reduce
  s += __shfl_xor(s, 32);
  ss += __shfl_xor(ss, 32);
  __shared__ float red[4][64];
  const int wave = tid >> 6, lane = tid & 63;
  if (lane < 32) {
    red[wave][lane] = s;
    red[wave][32 + lane] = ss;
  }
  __syncthreads();
  if (tid < 64) {
    float v = red[0][tid] + red[1][tid] + red[2][tid] + red[3][tid];
    // replica blockIdx&63: 64 blocks/address -> no hot-line serialization
    atomicAdd(&stats_rep[(blockIdx.x & (NREP - 1)) * 64 + tid], v);
  }
}

__global__ void finalize_kernel(const float* __restrict__ gamma,
                                const float* __restrict__ beta,
                                const float* __restrict__ stats_rep,
                                float* __restrict__ affine, float invN) {
  int c = threadIdx.x;
  if (c < CMLP) {
    float s = 0.f, ss = 0.f;
    for (int r = 0; r < NREP; r++) {
      s += stats_rep[r * 64 + c];
      ss += stats_rep[r * 64 + 32 + c];
    }
    float mean = s * invN;
    float var = ss * invN - mean * mean;          // biased, like jnp.var
    float sc = gamma[c] * rsqrtf(var + BN_EPS);
    affine[c] = sc;                               // scale
    affine[CMLP + c] = beta[c] - mean * sc;       // bias
  }
}

// word W holds channels (2W)&31, (2W)&31 + 1 of pillar W/16; writes float2
__global__ void __launch_bounds__(256) transform_kernel(
    const unsigned* __restrict__ in16w, const float* __restrict__ affine,
    float2* __restrict__ out2, int nwords) {
  int w = blockIdx.x * 256 + threadIdx.x;
  if (w < nwords) {
    unsigned u = in16w[w];
    int c0 = (w << 1) & 31;
    float v0 = 0.f, v1 = 0.f;  // u16==0 <=> empty -> 0 (max-then-relu floor)
    unsigned lo = u & 0xFFFFu, hi = u >> 16;
    if (lo) v0 = fmaxf(fmaf(fabsf(affine[c0]), dec16(lo), affine[CMLP + c0]), 0.f);
    if (hi) v1 = fmaxf(fmaf(fabsf(affine[c0 + 1]), dec16(hi), affine[CMLP + c0 + 1]), 0.f);
    out2[w] = make_float2(v0, v1);
  }
}

extern "C" void kernel_launch(void* const* d_in, const int* in_sizes, int n_in,
                              void* d_out, int out_size, void* d_ws, size_t ws_size,
                              hipStream_t stream) {
  const float* xyz = (const float*)d_in[0];
  const float* ptf = (const float*)d_in[1];
  const float* W1 = (const float*)d_in[2];
  const float* gamma = (const float*)d_in[3];
  const float* beta = (const float*)d_in[4];
  const int* pil = (const int*)d_in[5];
  const int* sidx = (const int*)d_in[6];

  int N = in_sizes[0] / 3;
  int nwords = out_size / 2;  // out_size = M*32 f32 elems; 2 ch per word

  // ws: [0,16KB) stats replicas; [16KB,+256B) affine; then out16 (out_size*2 B)
  char* wsp = (char*)d_ws;
  float* stats_rep = (float*)wsp;
  float* affine = (float*)(wsp + NREP * 64 * sizeof(float));
  unsigned* out16w = (unsigned*)(wsp + NREP * 64 * sizeof(float) + 256);

  hipMemsetAsync(stats_rep, 0, NREP * 64 * sizeof(float), stream);
  hipMemsetAsync(out16w, 0, (size_t)nwords * sizeof(unsigned), stream);

  scatter_stats_kernel<<<SCATB, 256, 0, stream>>>(xyz, ptf, W1, gamma, pil,
                                                  sidx, stats_rep, out16w, N);
  finalize_kernel<<<1, 64, 0, stream>>>(gamma, beta, stats_rep, affine,
                                        1.0f / (float)N);
  transform_kernel<<<(nwords + 255) / 256, 256, 0, stream>>>(
      out16w, affine, (float2*)d_out, nwords);
}

// Round 5
// 177.241 us; speedup vs baseline: 1.1269x; 1.1269x over previous
//
#include <hip/hip_runtime.h>

// PillarMaxPooling R17: XCD-partitioned scatter (migration elimination).
// Model (fits R12-R16): binding resource = cross-XCD 128B line MIGRATIONS.
// 800k random atomics from 8 XCDs onto 120k pillar-lines: ~7/8 of updates
// change owning XCD -> line write-back + re-fetch = ~90MB each way == the
// measured FETCH/WRITE 85MB. Ops don't matter (R13: x2.8 ops -> +10%),
// latency doesn't (R15), bytes/pillar don't (R16: 64B packing made it WORSE
// via false sharing -> write quantum is the 128B line; R12 layout optimal).
// Fix: pillar partition = m & 7; block b (de-facto XCD b&7, locality-only
// assumption) processes ONLY its partition's points. Each partition group
// (512 blocks) lane-parallel-scans ALL sidx (8x scan, L3-resident): 32
// pts/half-wave tested in ~6 instr, ballot -> iterate owned bits. Lines stay
// in one XCD's L2 -> atomics local, write-back = final 15.4MB only.
// Filter dropped (it only suppressed migrations). Each point processed
// exactly once globally -> stats fold unchanged.
// Ledger: R12 85.8us/172 best (filter+stats); R13 no-filter 94; R14 bucket
// 286; R15 pipeline 92; R16 f16-pack 108. Harness ~85us floor.

#define CMLP 32
#define BN_EPS 1e-3f
#define PSIZE 0.075f
#define XMIN -54.0f
#define YMIN -54.0f
#define CZ   -1.0f   // 0.5*(Z_MIN+Z_MAX)
#define NREP 64      // stats replicas (64 lines apart)
#define SCATB 4096

// monotone float<->uint order map; u==0 unreachable from real data -> empty sentinel
__device__ __forceinline__ unsigned enc_f(float x) {
  unsigned b = __float_as_uint(x);
  return (b & 0x80000000u) ? ~b : (b | 0x80000000u);
}
__device__ __forceinline__ float dec_f(unsigned u) {
  unsigned b = (u & 0x80000000u) ? (u & 0x7fffffffu) : ~u;
  return __uint_as_float(b);
}

__global__ void __launch_bounds__(256) scatter_stats_kernel(
    const float* __restrict__ xyz, const float* __restrict__ ptf,
    const float* __restrict__ W1, const float* __restrict__ gamma,
    const int* __restrict__ pil, const int* __restrict__ sidx,
    float* __restrict__ stats_rep, unsigned* __restrict__ outenc,
    int N, int chunk) {
  const int tid = threadIdx.x;
  const int c = tid & 31;           // channel == lane within half-wave
  const int half = tid & 32;        // 0 = lanes 0-31, 32 = lanes 32-63
  const int q = blockIdx.x & 7;     // pillar partition (de-facto XCD id)
  // scan id: 512 blocks per partition x 8 half-waves -> 4096 disjoint chunks
  const int sid = ((blockIdx.x >> 3) << 3) + (tid >> 5);
  const int base = sid * chunk;
  // folded weights: h = x*wx + y*wy + z*wz - cx*w0 - cy*w1 - CZ*w2 + ptf.w
  const float w0 = W1[0 * CMLP + c], w1 = W1[1 * CMLP + c];
  const float w2 = W1[2 * CMLP + c];
  const float wx = w0 + W1[3 * CMLP + c];
  const float wy = w1 + W1[4 * CMLP + c];
  const float wz = w2 + W1[5 * CMLP + c];
  const float nw0 = -w0, nw1 = -w1;
  const float cc0 = -CZ * w2;
  const float w6 = W1[6 * CMLP + c], w7 = W1[7 * CMLP + c];
  const float w8 = W1[8 * CMLP + c], w9 = W1[9 * CMLP + c];
  const float w10 = W1[10 * CMLP + c];
  const float sgn = (gamma[c] < 0.f) ? -1.f : 1.f;  // sign(sc)=sign(gamma)
  float s = 0.f, ss = 0.f;  // per-channel h moments (owned points only)

  // lane-parallel scan: lane l tests point base+i+l; batch of 32 per half-wave
  int i = 0;
  int idx = base + c;
  int mb = (idx < N) ? sidx[idx] : 0;
  bool vb = (c < chunk) && (idx < N);
  while (i < chunk) {
    const int inext = i + 32;
    // prefetch next batch before consuming current
    int mn = 0;
    bool vn = false;
    if (inext < chunk) {
      int idxn = base + inext + c;
      vn = (inext + c < chunk) && (idxn < N);
      mn = (idxn < N) ? sidx[idxn] : 0;
    }
    const bool own = vb && ((mb & 7) == q);
    unsigned long long bal = __ballot(own);
    unsigned mask = (unsigned)(bal >> half);  // this half-wave's 32 bits
    while (mask) {
      const int src = __ffs(mask) - 1;
      mask &= mask - 1;
      const int m = __shfl(mb, src + half);   // broadcast owned pillar
      const int p = base + i + src;           // its point index
      float cx = fmaf((float)pil[3 * m + 2] + 0.5f, PSIZE, XMIN);
      float cy = fmaf((float)pil[3 * m + 1] + 0.5f, PSIZE, YMIN);
      float x = xyz[3 * p], y = xyz[3 * p + 1], z = xyz[3 * p + 2];
      float h = cc0;
      h = fmaf(x, wx, h);
      h = fmaf(y, wy, h);
      h = fmaf(z, wz, h);
      h = fmaf(cx, nw0, h);
      h = fmaf(cy, nw1, h);
      h = fmaf(ptf[5 * p + 0], w6, h);
      h = fmaf(ptf[5 * p + 1], w7, h);
      h = fmaf(ptf[5 * p + 2], w8, h);
      h = fmaf(ptf[5 * p + 3], w9, h);
      h = fmaf(ptf[5 * p + 4], w10, h);
      s += h;
      ss = fmaf(h, h, ss);
      // local-XCD atomic: line owned by this partition's L2, no migration
      atomicMax(&outenc[m * CMLP + c], enc_f(sgn * h));
    }
    i = inext;
    mb = mn;
    vb = vn;
  }
  // lanes L and L+32 hold the same channel -> combine, stage, block-reduce
  s += __shfl_xor(s, 32);
  ss += __shfl_xor(ss, 32);
  __shared__ float red[4][64];
  const int wave = tid >> 6, lane = tid & 63;
  if (lane < 32) {
    red[wave][lane] = s;
    red[wave][32 + lane] = ss;
  }
  __syncthreads();
  if (tid < 64) {
    float v = red[0][tid] + red[1][tid] + red[2][tid] + red[3][tid];
    // replica blockIdx&63: 64 blocks/address -> no hot-line serialization
    atomicAdd(&stats_rep[(blockIdx.x & (NREP - 1)) * 64 + tid], v);
  }
}

__global__ void finalize_kernel(const float* __restrict__ gamma,
                                const float* __restrict__ beta,
                                const float* __restrict__ stats_rep,
                                float* __restrict__ affine, float invN) {
  int c = threadIdx.x;
  if (c < CMLP) {
    float s = 0.f, ss = 0.f;
    for (int r = 0; r < NREP; r++) {
      s += stats_rep[r * 64 + c];
      ss += stats_rep[r * 64 + 32 + c];
    }
    float mean = s * invN;
    float var = ss * invN - mean * mean;          // biased, like jnp.var
    float sc = gamma[c] * rsqrtf(var + BN_EPS);
    affine[c] = sc;                               // scale
    affine[CMLP + c] = beta[c] - mean * sc;       // bias
  }
}

__global__ void __launch_bounds__(256) transform_kernel(
    unsigned* __restrict__ io, const float* __restrict__ affine, int total) {
  int i = blockIdx.x * 256 + threadIdx.x;
  if (i < total) {
    unsigned u = io[i];
    int c = i & 31;
    float v = 0.f;  // u==0 <=> empty pillar -> 0 (matches max then relu floor)
    if (u) v = fmaxf(fmaf(fabsf(affine[c]), dec_f(u), affine[CMLP + c]), 0.f);
    io[i] = __float_as_uint(v);
  }
}

extern "C" void kernel_launch(void* const* d_in, const int* in_sizes, int n_in,
                              void* d_out, int out_size, void* d_ws, size_t ws_size,
                              hipStream_t stream) {
  const float* xyz = (const float*)d_in[0];
  const float* ptf = (const float*)d_in[1];
  const float* W1 = (const float*)d_in[2];
  const float* gamma = (const float*)d_in[3];
  const float* beta = (const float*)d_in[4];
  const int* pil = (const int*)d_in[5];
  const int* sidx = (const int*)d_in[6];
  unsigned* out = (unsigned*)d_out;

  int N = in_sizes[0] / 3;
  int chunk = (N + SCATB - 1) / SCATB;  // points per scan-chunk (4096 chunks)

  // ws: [0, 16KB) stats replicas (64 x {s[32], ss[32]}); [16KB, +256B) affine
  float* stats_rep = (float*)d_ws;
  float* affine = (float*)((char*)d_ws + NREP * 64 * sizeof(float));

  hipMemsetAsync(stats_rep, 0, NREP * 64 * sizeof(float), stream);
  hipMemsetAsync(out, 0, (size_t)out_size * sizeof(unsigned), stream);

  scatter_stats_kernel<<<SCATB, 256, 0, stream>>>(xyz, ptf, W1, gamma, pil,
                                                  sidx, stats_rep, out, N,
                                                  chunk);
  finalize_kernel<<<1, 64, 0, stream>>>(gamma, beta, stats_rep, affine,
                                        1.0f / (float)N);
  transform_kernel<<<(out_size + 255) / 256, 256, 0, stream>>>(out, affine,
                                                               out_size);
}